// Round 4
// baseline (665.943 us; speedup 1.0000x reference)
//
#include <hip/hip_runtime.h>
#include <hip/hip_cooperative_groups.h>

namespace cg = cooperative_groups;

#define LBL 32
#define NPIX (736 * 736)   // 541696
#define NQ (NPIX / 4)      // 135424 = 529*256 exactly
#define NGRP 529           // 256-quad groups per batch (exact, no ragged tail)
#define BATCH 8
#define DELTA_AGG 0.5f
#define DELTA_DIS 1.5f
#define REG_W 0.001f

// ---------- fallback (round-2 proven) geometry ----------
#define QPB 512            // quads per block (2 per thread)
#define NBA 265            // ceil(NQ/QPB)
#define LAB_BASE 0
#define PA_BASE (BATCH * NQ)                    // 1083392
#define RED_BASE (PA_BASE + BATCH * NBA * 192)  // 1490432
#define PC_BASE (RED_BASE + BATCH * 256)        // 1492480
// fallback end: 1560320 floats = 6.24 MB

// ---------- fused geometry ----------
#define QPT 6              // quad-groups per thread
#define NBB 96             // blocks per batch; 96*6=576 >= 529 groups
#define FPA_BASE 1600000                         // after fallback region
#define FRED_BASE (FPA_BASE + BATCH * NBB * 192) // +147456
#define FPC_BASE (FRED_BASE + BATCH * 256)
// fused end: FPC_BASE + 8*96*32 = 1774080 floats = 7.1 MB

__device__ __forceinline__ unsigned short f2bf(float f) {  // RTNE
  unsigned int u = __float_as_uint(f);
  unsigned int r = u + 0x7FFFu + ((u >> 16) & 1u);
  return (unsigned short)(r >> 16);
}
__device__ __forceinline__ float bfl(unsigned int w) {
  return __uint_as_float(w << 16);
}
__device__ __forceinline__ float bfh(unsigned int w) {
  return __uint_as_float(w & 0xFFFF0000u);
}

// ============================================================================
// FUSED cooperative kernel: histogram -> reduce -> agg -> finalize
// grid (NBB, BATCH) = 768 blocks x 256 thr; __launch_bounds__(256,3) caps
// VGPR ~168 so runtime occupancy >= 3 blocks/CU -> 768 co-resident guaranteed.
// Each thread holds 24 px as packed bf16 (48 VGPR) + labels (6 VGPR) across
// grid syncs, so phase C re-reads NOTHING from memory.
// ============================================================================
__global__ __launch_bounds__(256, 3) void kF(
    const float* __restrict__ emb, const int* __restrict__ inst,
    const float* __restrict__ kern, const float* __restrict__ mask,
    float* __restrict__ ws, float* __restrict__ out) {
  const int bx = blockIdx.x;  // 0..NBB-1
  const int by = blockIdx.y;  // batch
  const int t = threadIdx.x;

  __shared__ float s_cnt[LBL];      // [0] = "saw label 0" flag
  __shared__ float s_sum[4 * 33];   // padded [comp][label]
  __shared__ float s_cta[LBL];      // mask-only counts (cnt_a)
  __shared__ float s_mean[LBL * 4];
  __shared__ float s_val[LBL];
  __shared__ float redl[LBL][9];
  __shared__ float sv[LBL];

  if (t < LBL) { s_cnt[t] = 0.f; s_cta[t] = 0.f; }
  if (t < 4 * 33) s_sum[t] = 0.f;
  __syncthreads();

  const long base = (long)by * NPIX;
  const float* ebase = emb + (long)by * 4 * NPIX;
  const int4* ip = (const int4*)(inst + base);
  const float4* kp = (const float4*)(kern + base);
  const float4* mp = (const float4*)(mask + base);
  const float4* p0 = (const float4*)(ebase);
  const float4* p1 = (const float4*)(ebase + NPIX);
  const float4* p2 = (const float4*)(ebase + 2 * NPIX);
  const float4* p3 = (const float4*)(ebase + 3 * NPIX);

  uint2 pk[QPT][4];        // held bf16 pixels (fully unrolled -> static idx)
  unsigned int labw[QPT];  // held packed labels
  bool has0 = false;

  // ---- Phase A: load + histogram + pack-to-registers ----
#pragma unroll
  for (int k = 0; k < QPT; k++) {
    const int grp = bx * QPT + k;        // block-uniform validity
    if (grp < NGRP) {
      const int q = grp * 256 + t;
      const int4 iv = ip[q];
      const float4 kv = kp[q], mv = mp[q];
      const float4 e0 = p0[q], e1 = p1[q], e2 = p2[q], e3 = p3[q];
      const int labs[4] = {iv.x, iv.y, iv.z, iv.w};
      const float ks[4] = {kv.x, kv.y, kv.z, kv.w};
      const float ms[4] = {mv.x, mv.y, mv.z, mv.w};
      const float c0[4] = {e0.x, e0.y, e0.z, e0.w};
      const float c1[4] = {e1.x, e1.y, e1.z, e1.w};
      const float c2[4] = {e2.x, e2.y, e2.z, e2.w};
      const float c3[4] = {e3.x, e3.y, e3.z, e3.w};
      unsigned int lw = 0;
#pragma unroll
      for (int j = 0; j < 4; j++) {
        const bool m = ms[j] > 0.5f;
        const int li = m ? labs[j] : 0;
        const bool kf = m && (ks[j] > 0.5f);
        lw |= ((unsigned int)li) << (8 * j);
        pk[k][j].x = ((unsigned int)f2bf(c0[j])) |
                     (((unsigned int)f2bf(c1[j])) << 16);
        pk[k][j].y = ((unsigned int)f2bf(c2[j])) |
                     (((unsigned int)f2bf(c3[j])) << 16);
        if (li > 0) {
          atomicAdd(&s_cta[li], 1.0f);
          if (kf) {
            atomicAdd(&s_cnt[li], 1.0f);
            atomicAdd(&s_sum[0 * 33 + li], c0[j]);
            atomicAdd(&s_sum[1 * 33 + li], c1[j]);
            atomicAdd(&s_sum[2 * 33 + li], c2[j]);
            atomicAdd(&s_sum[3 * 33 + li], c3[j]);
          } else has0 = true;
        } else has0 = true;
      }
      labw[k] = lw;
    } else {
      labw[k] = 0;
    }
  }

  if (has0) s_cnt[0] = 1.0f;  // benign race
  __syncthreads();
  {  // block-major coalesced partial store; linearize padded sums to l*4+c
    float* po = ws + FPA_BASE + ((size_t)by * NBB + bx) * 192;
    if (t < 192) {
      float v;
      if (t < 32) v = s_cnt[t];
      else if (t < 160) {
        const int e = t - 32;
        v = s_sum[(e & 3) * 33 + (e >> 2)];
      } else {
        v = s_cta[t - 160];
      }
      po[t] = v;
    }
  }

  __threadfence();
  cg::this_grid().sync();

  // ---- Phase B: reduce partials; wave gw owns one (batch, elem) column ----
  {
    const int gw = ((by * NBB + bx) << 2) + (t >> 6);  // 3072 waves >= 1536
    const int lane = t & 63;
    if (gw < BATCH * 192) {
      const int b = gw / 192, col = gw - b * 192;
      const float* pa = ws + FPA_BASE + (size_t)b * NBB * 192 + col;
      float s = 0.f;
      for (int g = lane; g < NBB; g += 64) s += pa[(size_t)g * 192];
#pragma unroll
      for (int o = 32; o > 0; o >>= 1) s += __shfl_down(s, o);
      if (lane == 0) ws[FRED_BASE + b * 256 + col] = s;  // raw totals
    }
  }

  __threadfence();
  cg::this_grid().sync();

  // ---- Phase C: aggregation vals from REGISTERS (no memory re-read) ----
  {
    const float* rd = ws + FRED_BASE + by * 256;
    if (t < LBL * 4) {
      const int l = t >> 2;
      s_mean[t] = (l == 0) ? 0.f : rd[32 + t] / fmaxf(rd[l], 1.0f);
    }
    if (t < LBL) s_val[t] = 0.f;
    __syncthreads();

#pragma unroll
    for (int k = 0; k < QPT; k++) {
      const int grp = bx * QPT + k;
      if (grp < NGRP) {
#pragma unroll
        for (int j = 0; j < 4; j++) {
          const int li = (labw[k] >> (8 * j)) & 0xFF;
          if (li > 0) {
            const float d0 = bfl(pk[k][j].x) - s_mean[li * 4 + 0];
            const float d1 = bfh(pk[k][j].x) - s_mean[li * 4 + 1];
            const float d2 = bfl(pk[k][j].y) - s_mean[li * 4 + 2];
            const float d3 = bfh(pk[k][j].y) - s_mean[li * 4 + 3];
            const float sq = d0 * d0 + d1 * d1 + d2 * d2 + d3 * d3;
            const float dist = (sq > 0.f) ? sqrtf(sq) : 0.f;
            const float tt = fmaxf(dist - DELTA_AGG, 0.f);
            atomicAdd(&s_val[li], logf(fmaf(tt, tt, 1.0f)));
          }
        }
      }
    }
    __syncthreads();
    if (t < 32) ws[FPC_BASE + ((size_t)by * NBB + bx) * 32 + t] = s_val[t];
  }

  __threadfence();
  cg::this_grid().sync();

  // ---- Phase D: 8 blocks finalize (one per batch) ----
  if (by == 0 && bx < BATCH) {
    const int b2 = bx;
    const int col = t >> 3, sub = t & 7;  // 32 cols x 8 chunks
    const float* pc = ws + FPC_BASE + (size_t)b2 * NBB * 32 + col;
    float s = 0.f;
    for (int g = sub; g < NBB; g += 8) s += pc[(size_t)g * 32];
    redl[col][sub] = s;

    const float* rd2 = ws + FRED_BASE + b2 * 256;
    if (t < 128) {
      const int l = t >> 2;
      s_mean[t] = (l == 0) ? 0.f : rd2[32 + t] / fmaxf(rd2[l], 1.0f);
    } else if (t < 160) {
      s_cnt[t - 128] = rd2[t - 128];          // cnt_k (incl. label-0 flag)
    } else if (t < 192) {
      s_cta[t - 160] = rd2[160 + (t - 160)];  // cnt_a
    }
    __syncthreads();
    if (t < 32) {
      float v = 0.f;
#pragma unroll
      for (int k2 = 0; k2 < 8; k2++) v += redl[t][k2];
      sv[t] = v;
    }
    __syncthreads();

    if (t < 64) {  // wave 0 only
      const int lane = t;
      const bool pres = (lane < LBL) && (s_cnt[lane & 31] > 0.f);
      const unsigned long long bal_p = __ballot(pres);
      const int num_instance = __popcll(bal_p);
      const bool nz = pres && (lane > 0);
      const unsigned long long bal_nz = __ballot(nz);

      float agg = 0.f;
      if (nz) agg = sv[lane] / fmaxf(s_cta[lane], 1.0f);

      float reg = 0.f;
      if (pres) {
        float sq = 0.f;
#pragma unroll
        for (int d = 0; d < 4; d++) sq += s_mean[lane * 4 + d] * s_mean[lane * 4 + d];
        const float nrm = (sq > 0.f) ? sqrtf(sq) : 0.f;
        reg = logf(nrm + 1.0f);
      }

      float dis = 0.f, npair = 0.f;
      for (int pi = lane; pi < LBL * LBL; pi += 64) {
        const int i = pi >> 5, j = pi & 31;
        if (i != j && ((bal_nz >> i) & 1ull) && ((bal_nz >> j) & 1ull)) {
          float sq = 0.f;
#pragma unroll
          for (int d = 0; d < 4; d++) {
            const float df = s_mean[i * 4 + d] - s_mean[j * 4 + d];
            sq += df * df;
          }
          const float pdist = (sq > 0.f) ? sqrtf(sq) : 0.f;
          const float tt = fmaxf(2.0f * DELTA_DIS - pdist, 0.f);
          dis += logf(fmaf(tt, tt, 1.0f));
          npair += 1.0f;
        }
      }

#pragma unroll
      for (int o = 32; o > 0; o >>= 1) {
        agg += __shfl_down(agg, o);
        reg += __shfl_down(reg, o);
        dis += __shfl_down(dis, o);
        npair += __shfl_down(npair, o);
      }

      if (lane == 0) {
        const float l_agg = agg / fmaxf((float)(num_instance - 1), 1.0f);
        const float l_dis = (num_instance > 2) ? dis / fmaxf(npair, 1.0f) : 0.f;
        const float l_reg = reg / fmaxf((float)num_instance, 1.0f) * REG_W;
        const float loss = l_agg + l_dis + l_reg;
        out[b2] = (num_instance <= 1) ? 0.f : loss;
      }
    }
  }
}

// ============================================================================
// FALLBACK: round-2 proven 4-kernel chain (used iff cooperative launch fails)
// ============================================================================
__device__ __forceinline__ unsigned int procQuad(
    const int4 iv, const float4 kv, const float4 mv,
    const float4 e0, const float4 e1, const float4 e2, const float4 e3,
    float* __restrict__ s_cnt, float* __restrict__ s_sum,
    float* __restrict__ s_cta, bool& has0) {
  const int labs[4] = {iv.x, iv.y, iv.z, iv.w};
  const float ks[4] = {kv.x, kv.y, kv.z, kv.w};
  const float ms[4] = {mv.x, mv.y, mv.z, mv.w};
  const float c0[4] = {e0.x, e0.y, e0.z, e0.w};
  const float c1[4] = {e1.x, e1.y, e1.z, e1.w};
  const float c2[4] = {e2.x, e2.y, e2.z, e2.w};
  const float c3[4] = {e3.x, e3.y, e3.z, e3.w};
  unsigned int labw = 0;
#pragma unroll
  for (int j = 0; j < 4; j++) {
    const bool m = ms[j] > 0.5f;
    const int li = m ? labs[j] : 0;
    const bool kf = m && (ks[j] > 0.5f);
    labw |= ((unsigned int)li) << (8 * j);
    if (li > 0) {
      atomicAdd(&s_cta[li], 1.0f);
      if (kf) {
        atomicAdd(&s_cnt[li], 1.0f);
        atomicAdd(&s_sum[0 * 33 + li], c0[j]);
        atomicAdd(&s_sum[1 * 33 + li], c1[j]);
        atomicAdd(&s_sum[2 * 33 + li], c2[j]);
        atomicAdd(&s_sum[3 * 33 + li], c3[j]);
      } else has0 = true;
    } else has0 = true;
  }
  return labw;
}

__global__ __launch_bounds__(256) void kA(
    const float* __restrict__ emb, const int* __restrict__ inst,
    const float* __restrict__ kern, const float* __restrict__ mask,
    float* __restrict__ ws) {
  const int b = blockIdx.y;
  const int t = threadIdx.x;
  __shared__ float s_cnt[LBL];
  __shared__ float s_sum[4 * 33];
  __shared__ float s_cta[LBL];
  if (t < LBL) { s_cnt[t] = 0.f; s_cta[t] = 0.f; }
  if (t < 4 * 33) s_sum[t] = 0.f;
  __syncthreads();

  const long base = (long)b * NPIX;
  const float* ebase = emb + (long)b * 4 * NPIX;
  const int4* ip = (const int4*)(inst + base);
  const float4* kp = (const float4*)(kern + base);
  const float4* mp = (const float4*)(mask + base);
  const float4* p0 = (const float4*)(ebase);
  const float4* p1 = (const float4*)(ebase + NPIX);
  const float4* p2 = (const float4*)(ebase + 2 * NPIX);
  const float4* p3 = (const float4*)(ebase + 3 * NPIX);

  const int q0 = blockIdx.x * QPB + t;
  const int q1 = q0 + 256;
  const bool v1 = (q1 < NQ);

  const int4 iva = ip[q0];
  const float4 kva = kp[q0], mva = mp[q0];
  const float4 ea0 = p0[q0], ea1 = p1[q0], ea2 = p2[q0], ea3 = p3[q0];
  int4 ivb;
  float4 kvb, mvb, fb0, fb1, fb2, fb3;
  if (v1) {
    ivb = ip[q1]; kvb = kp[q1]; mvb = mp[q1];
    fb0 = p0[q1]; fb1 = p1[q1]; fb2 = p2[q1]; fb3 = p3[q1];
  }

  bool has0 = false;
  unsigned int* labp = (unsigned int*)(ws + LAB_BASE) + (size_t)b * NQ;
  labp[q0] = procQuad(iva, kva, mva, ea0, ea1, ea2, ea3, s_cnt, s_sum, s_cta, has0);
  if (v1)
    labp[q1] = procQuad(ivb, kvb, mvb, fb0, fb1, fb2, fb3, s_cnt, s_sum, s_cta, has0);

  if (has0) s_cnt[0] = 1.0f;
  __syncthreads();
  float* po = ws + PA_BASE + ((size_t)b * NBA + blockIdx.x) * 192;
  if (t < 192) {
    float v;
    if (t < 32) v = s_cnt[t];
    else if (t < 160) {
      const int e = t - 32;
      v = s_sum[(e & 3) * 33 + (e >> 2)];
    } else v = s_cta[t - 160];
    po[t] = v;
  }
}

__global__ __launch_bounds__(256) void kB(float* __restrict__ ws) {
  const int b = blockIdx.y;
  const int col = blockIdx.x * 4 + (threadIdx.x >> 6);
  const int lane = threadIdx.x & 63;
  const float* pa = ws + PA_BASE + (size_t)b * NBA * 192 + col;
  float s = 0.f;
  for (int g = lane; g < NBA; g += 64) s += pa[(size_t)g * 192];
#pragma unroll
  for (int o = 32; o > 0; o >>= 1) s += __shfl_down(s, o);
  if (lane == 0) ws[RED_BASE + b * 256 + col] = s;
}

__device__ __forceinline__ void aggQuadF(const unsigned int lw,
    const float4 e0, const float4 e1, const float4 e2, const float4 e3,
    const float* __restrict__ s_mean, float* __restrict__ s_val) {
  const float c0[4] = {e0.x, e0.y, e0.z, e0.w};
  const float c1[4] = {e1.x, e1.y, e1.z, e1.w};
  const float c2[4] = {e2.x, e2.y, e2.z, e2.w};
  const float c3[4] = {e3.x, e3.y, e3.z, e3.w};
#pragma unroll
  for (int j = 0; j < 4; j++) {
    const int li = (lw >> (8 * j)) & 0xFF;
    if (li > 0) {
      const float d0 = c0[j] - s_mean[li * 4 + 0];
      const float d1 = c1[j] - s_mean[li * 4 + 1];
      const float d2 = c2[j] - s_mean[li * 4 + 2];
      const float d3 = c3[j] - s_mean[li * 4 + 3];
      const float sq = d0 * d0 + d1 * d1 + d2 * d2 + d3 * d3;
      const float dist = (sq > 0.f) ? sqrtf(sq) : 0.f;
      const float tt = fmaxf(dist - DELTA_AGG, 0.f);
      atomicAdd(&s_val[li], logf(fmaf(tt, tt, 1.0f)));
    }
  }
}

__global__ __launch_bounds__(256) void kC(const float* __restrict__ emb,
                                          float* __restrict__ ws) {
  const int b = blockIdx.y;
  const int t = threadIdx.x;
  __shared__ float s_mean[LBL * 4];
  __shared__ float s_val[LBL];
  const float* rd = ws + RED_BASE + b * 256;
  if (t < LBL * 4) {
    const int l = t >> 2;
    s_mean[t] = (l == 0) ? 0.f : rd[32 + t] / fmaxf(rd[l], 1.0f);
  }
  if (t < LBL) s_val[t] = 0.f;
  __syncthreads();

  const unsigned int* labp = (const unsigned int*)(ws + LAB_BASE) + (size_t)b * NQ;
  const float* ebase = emb + (long)b * 4 * NPIX;
  const float4* p0 = (const float4*)(ebase);
  const float4* p1 = (const float4*)(ebase + NPIX);
  const float4* p2 = (const float4*)(ebase + 2 * NPIX);
  const float4* p3 = (const float4*)(ebase + 3 * NPIX);
  const int q0 = blockIdx.x * QPB + t;
  const int q1 = q0 + 256;
  const bool v1 = (q1 < NQ);

  const unsigned int lwa = labp[q0];
  const float4 ea0 = p0[q0], ea1 = p1[q0], ea2 = p2[q0], ea3 = p3[q0];
  unsigned int lwb = 0;
  float4 fb0, fb1, fb2, fb3;
  if (v1) {
    lwb = labp[q1];
    fb0 = p0[q1]; fb1 = p1[q1]; fb2 = p2[q1]; fb3 = p3[q1];
  }

  aggQuadF(lwa, ea0, ea1, ea2, ea3, s_mean, s_val);
  if (v1) aggQuadF(lwb, fb0, fb1, fb2, fb3, s_mean, s_val);

  __syncthreads();
  float* po = ws + PC_BASE + ((size_t)b * NBA + blockIdx.x) * 32;
  if (t < 32) po[t] = s_val[t];
}

__global__ __launch_bounds__(1024) void kD(const float* __restrict__ ws,
                                           float* __restrict__ out) {
  const int b = blockIdx.x;
  const int t = threadIdx.x;
  const int col = t >> 5, sub = t & 31;
  const float* pc = ws + PC_BASE + (size_t)b * NBA * 32 + col;
  float s = 0.f;
  for (int g = sub; g < NBA; g += 32) s += pc[(size_t)g * 32];
  __shared__ float red[LBL][33];
  red[col][sub] = s;

  const float* rd = ws + RED_BASE + b * 256;
  __shared__ float sm[LBL * 4];
  __shared__ float scc[LBL];
  __shared__ float sca[LBL];
  if (t >= 512 && t < 640) {
    const int e = t - 512, l = e >> 2;
    sm[e] = (l == 0) ? 0.f : rd[32 + e] / fmaxf(rd[l], 1.0f);
  } else if (t >= 640 && t < 672) {
    scc[t - 640] = rd[t - 640];
  } else if (t >= 672 && t < 704) {
    sca[t - 672] = rd[160 + (t - 672)];
  }
  __syncthreads();
  __shared__ float sv[LBL];
  if (t < 32) {
    float v = 0.f;
#pragma unroll
    for (int k = 0; k < 32; k++) v += red[t][k];
    sv[t] = v;
  }
  __syncthreads();

  if (t < 64) {
    const int lane = t;
    const bool pres = (lane < LBL) && (scc[lane & 31] > 0.f);
    const unsigned long long bal_p = __ballot(pres);
    const int num_instance = __popcll(bal_p);
    const bool nz = pres && (lane > 0);
    const unsigned long long bal_nz = __ballot(nz);

    float agg = 0.f;
    if (nz) agg = sv[lane] / fmaxf(sca[lane], 1.0f);

    float reg = 0.f;
    if (pres) {
      float sq = 0.f;
#pragma unroll
      for (int d = 0; d < 4; d++) sq += sm[lane * 4 + d] * sm[lane * 4 + d];
      const float nrm = (sq > 0.f) ? sqrtf(sq) : 0.f;
      reg = logf(nrm + 1.0f);
    }

    float dis = 0.f, npair = 0.f;
    for (int pi = lane; pi < LBL * LBL; pi += 64) {
      const int i = pi >> 5, j = pi & 31;
      if (i != j && ((bal_nz >> i) & 1ull) && ((bal_nz >> j) & 1ull)) {
        float sq = 0.f;
#pragma unroll
        for (int d = 0; d < 4; d++) {
          const float df = sm[i * 4 + d] - sm[j * 4 + d];
          sq += df * df;
        }
        const float pdist = (sq > 0.f) ? sqrtf(sq) : 0.f;
        const float tt = fmaxf(2.0f * DELTA_DIS - pdist, 0.f);
        dis += logf(fmaf(tt, tt, 1.0f));
        npair += 1.0f;
      }
    }

#pragma unroll
    for (int o = 32; o > 0; o >>= 1) {
      agg += __shfl_down(agg, o);
      reg += __shfl_down(reg, o);
      dis += __shfl_down(dis, o);
      npair += __shfl_down(npair, o);
    }

    if (lane == 0) {
      const float l_agg = agg / fmaxf((float)(num_instance - 1), 1.0f);
      const float l_dis = (num_instance > 2) ? dis / fmaxf(npair, 1.0f) : 0.f;
      const float l_reg = reg / fmaxf((float)num_instance, 1.0f) * REG_W;
      const float loss = l_agg + l_dis + l_reg;
      out[b] = (num_instance <= 1) ? 0.f : loss;
    }
  }
}

extern "C" void kernel_launch(void* const* d_in, const int* in_sizes, int n_in,
                              void* d_out, int out_size, void* d_ws,
                              size_t ws_size, hipStream_t stream) {
  const float* emb = (const float*)d_in[0];
  const int* instance = (const int*)d_in[1];
  const float* kern = (const float*)d_in[2];
  const float* mask = (const float*)d_in[3];
  float* out = (float*)d_out;
  float* ws = (float*)d_ws;

  // Try the fused cooperative kernel; on ANY failure fall back to the
  // proven 4-kernel chain (disjoint ws regions, same results).
  dim3 grid(NBB, BATCH);  // 768 blocks @ >=3 blocks/CU -> co-residency safe
  dim3 block(256);
  void* args[] = {(void*)&emb, (void*)&instance, (void*)&kern,
                  (void*)&mask, (void*)&ws,      (void*)&out};
  hipError_t rc =
      hipLaunchCooperativeKernel((void*)kF, grid, block, args, 0, stream);
  if (rc != hipSuccess) {
    dim3 gridA(NBA, BATCH);
    kA<<<gridA, 256, 0, stream>>>(emb, instance, kern, mask, ws);
    dim3 gridB(48, BATCH);
    kB<<<gridB, 256, 0, stream>>>(ws);
    kC<<<gridA, 256, 0, stream>>>(emb, ws);
    kD<<<BATCH, 1024, 0, stream>>>(ws, out);
  }
}

// Round 7
// 260.372 us; speedup vs baseline: 2.5577x; 2.5577x over previous
//
#include <hip/hip_runtime.h>

#define LBL 32
#define NPIX (736 * 736)   // 541696
#define NQ (NPIX / 4)      // 135424 float4-quads per batch
#define QPB 512            // quads per block (2 per thread)
#define NBA 265            // ceil(NQ/QPB); block 264: only first quad-set valid
#define BATCH 8
#define DELTA_AGG 0.5f
#define DELTA_DIS 1.5f
#define REG_W 0.001f

// ws layout (float indices) — production (round-2 proven, ~6.2 MB):
#define LAB_BASE 0
#define PA_BASE (BATCH * NQ)                    // 1083392
#define RED_BASE (PA_BASE + BATCH * NBA * 192)  // 1490432
#define PC_BASE (RED_BASE + BATCH * 256)        // 1492480
// ablation dummy regions (never read; round-0 proved ws >= 41 MB usable):
#define DUMA_BASE 1700000    // per-thread acc store (kA_noat): +542720
#define DUMLAB_BASE 2300000  // labw dummy spill (kA_noat): +1083392
#define DUMPA_BASE 3400000   // partial-store dummy (both ablations): +407040
// end ~3.81M floats = 15.3 MB

// ===========================================================================
// ABLATION 1: kA_synld — kA's EXACT LDS-atomic structure, synthetic labels/
// values from a hash, ZERO global loads. Isolates atomic+VALU cost.
// Signature in counters: FETCH_SIZE ~ 0.
// ===========================================================================
#define SYNPX(Q, J)                                                           \
  {                                                                           \
    unsigned h = ((unsigned)((Q)*4 + (J)) ^ (unsigned)(b * 0x1000193));       \
    h *= 2654435761u; h ^= h >> 16; h *= 0x85EBCA6Bu; h ^= h >> 13;           \
    const int li = ((h >> 5) & 1) ? (int)(h & 31) : 0;   /* p(li>0)=.484 */   \
    const bool kf = ((h >> 5) & 1) && ((h >> 6) & 1);    /* p(kf)=.242  */    \
    const float c0 = (float)((h >> 8) & 255) * 0.0078125f - 1.f;              \
    const float c1 = (float)((h >> 16) & 255) * 0.0078125f - 1.f;             \
    const float c2 = (float)((h >> 24) & 255) * 0.0078125f - 1.f;             \
    const float c3 = (float)(h & 255) * 0.0078125f - 1.f;                     \
    if (li > 0) {                                                             \
      atomicAdd(&s_cta[li], 1.0f);                                            \
      if (kf) {                                                               \
        atomicAdd(&s_cnt[li], 1.0f);                                          \
        atomicAdd(&s_sum[0 * 33 + li], c0);                                   \
        atomicAdd(&s_sum[1 * 33 + li], c1);                                   \
        atomicAdd(&s_sum[2 * 33 + li], c2);                                   \
        atomicAdd(&s_sum[3 * 33 + li], c3);                                   \
      } else has0 = true;                                                     \
    } else has0 = true;                                                       \
  }

__global__ __launch_bounds__(256) void kA_synld(float* __restrict__ ws) {
  const int b = blockIdx.y;
  const int t = threadIdx.x;
  __shared__ float s_cnt[LBL];
  __shared__ float s_sum[4 * 33];
  __shared__ float s_cta[LBL];
  if (t < LBL) { s_cnt[t] = 0.f; s_cta[t] = 0.f; }
  if (t < 4 * 33) s_sum[t] = 0.f;
  __syncthreads();

  const int q0 = blockIdx.x * QPB + t;
  const int q1 = q0 + 256;
  const bool v1 = (q1 < NQ);
  bool has0 = false;

  SYNPX(q0, 0) SYNPX(q0, 1) SYNPX(q0, 2) SYNPX(q0, 3)
  if (v1) { SYNPX(q1, 0) SYNPX(q1, 1) SYNPX(q1, 2) SYNPX(q1, 3) }

  if (has0) s_cnt[0] = 1.0f;
  __syncthreads();
  float* po = ws + DUMPA_BASE + ((size_t)b * NBA + blockIdx.x) * 192;
  if (t < 192) {
    float v;
    if (t < 32) v = s_cnt[t];
    else if (t < 160) {
      const int e = t - 32;
      v = s_sum[(e & 3) * 33 + (e >> 2)];
    } else v = s_cta[t - 160];
    po[t] = v;
  }
}

// ===========================================================================
// ABLATION 2: kA_noat — kA's EXACT loads + label compute + spill stores,
// atomics replaced by live register accumulation. Isolates load+VALU cost.
// Signature: FETCH_SIZE ~ 59 MB, no LDS traffic.
// ===========================================================================
__device__ __forceinline__ unsigned int procQuadNA(
    const int4 iv, const float4 kv, const float4 mv,
    const float4 e0, const float4 e1, const float4 e2, const float4 e3,
    float& acc, float& acck) {
  const int labs[4] = {iv.x, iv.y, iv.z, iv.w};
  const float ks[4] = {kv.x, kv.y, kv.z, kv.w};
  const float ms[4] = {mv.x, mv.y, mv.z, mv.w};
  const float c0[4] = {e0.x, e0.y, e0.z, e0.w};
  const float c1[4] = {e1.x, e1.y, e1.z, e1.w};
  const float c2[4] = {e2.x, e2.y, e2.z, e2.w};
  const float c3[4] = {e3.x, e3.y, e3.z, e3.w};
  unsigned int labw = 0;
#pragma unroll
  for (int j = 0; j < 4; j++) {
    const bool m = ms[j] > 0.5f;
    const int li = m ? labs[j] : 0;
    const bool kf = m && (ks[j] > 0.5f);
    labw |= ((unsigned int)li) << (8 * j);
    if (li > 0) {
      acc += 1.0f;
      if (kf) {
        acck += c0[j] + c1[j] + c2[j] + c3[j];  // keeps all four comps live
      } else acc += 0.5f;
    } else acc += 0.25f;
  }
  return labw;
}

__global__ __launch_bounds__(256) void kA_noat(
    const float* __restrict__ emb, const int* __restrict__ inst,
    const float* __restrict__ kern, const float* __restrict__ mask,
    float* __restrict__ ws) {
  const int b = blockIdx.y;
  const int t = threadIdx.x;

  const long base = (long)b * NPIX;
  const float* ebase = emb + (long)b * 4 * NPIX;
  const int4* ip = (const int4*)(inst + base);
  const float4* kp = (const float4*)(kern + base);
  const float4* mp = (const float4*)(mask + base);
  const float4* p0 = (const float4*)(ebase);
  const float4* p1 = (const float4*)(ebase + NPIX);
  const float4* p2 = (const float4*)(ebase + 2 * NPIX);
  const float4* p3 = (const float4*)(ebase + 3 * NPIX);

  const int q0 = blockIdx.x * QPB + t;
  const int q1 = q0 + 256;
  const bool v1 = (q1 < NQ);

  const int4 iva = ip[q0];
  const float4 kva = kp[q0], mva = mp[q0];
  const float4 ea0 = p0[q0], ea1 = p1[q0], ea2 = p2[q0], ea3 = p3[q0];
  int4 ivb;
  float4 kvb, mvb, fb0, fb1, fb2, fb3;
  if (v1) {
    ivb = ip[q1]; kvb = kp[q1]; mvb = mp[q1];
    fb0 = p0[q1]; fb1 = p1[q1]; fb2 = p2[q1]; fb3 = p3[q1];
  }

  float acc = 0.f, acck = 0.f;
  unsigned int* labp = (unsigned int*)(ws + DUMLAB_BASE) + (size_t)b * NQ;
  labp[q0] = procQuadNA(iva, kva, mva, ea0, ea1, ea2, ea3, acc, acck);
  if (v1)
    labp[q1] = procQuadNA(ivb, kvb, mvb, fb0, fb1, fb2, fb3, acc, acck);

  // live store of the accumulators (prevents DCE of loads/compute)
  ws[DUMA_BASE + ((size_t)b * NBA + blockIdx.x) * 256 + t] =
      acc + acck * 0.001f;
}

// ===========================================================================
// PRODUCTION: round-2 proven chain, byte-identical behavior (186 us, passes)
// ===========================================================================
__device__ __forceinline__ unsigned int procQuad(
    const int4 iv, const float4 kv, const float4 mv,
    const float4 e0, const float4 e1, const float4 e2, const float4 e3,
    float* __restrict__ s_cnt, float* __restrict__ s_sum,
    float* __restrict__ s_cta, bool& has0) {
  const int labs[4] = {iv.x, iv.y, iv.z, iv.w};
  const float ks[4] = {kv.x, kv.y, kv.z, kv.w};
  const float ms[4] = {mv.x, mv.y, mv.z, mv.w};
  const float c0[4] = {e0.x, e0.y, e0.z, e0.w};
  const float c1[4] = {e1.x, e1.y, e1.z, e1.w};
  const float c2[4] = {e2.x, e2.y, e2.z, e2.w};
  const float c3[4] = {e3.x, e3.y, e3.z, e3.w};
  unsigned int labw = 0;
#pragma unroll
  for (int j = 0; j < 4; j++) {
    const bool m = ms[j] > 0.5f;
    const int li = m ? labs[j] : 0;
    const bool kf = m && (ks[j] > 0.5f);
    labw |= ((unsigned int)li) << (8 * j);
    if (li > 0) {
      atomicAdd(&s_cta[li], 1.0f);
      if (kf) {
        atomicAdd(&s_cnt[li], 1.0f);
        atomicAdd(&s_sum[0 * 33 + li], c0[j]);
        atomicAdd(&s_sum[1 * 33 + li], c1[j]);
        atomicAdd(&s_sum[2 * 33 + li], c2[j]);
        atomicAdd(&s_sum[3 * 33 + li], c3[j]);
      } else has0 = true;
    } else has0 = true;
  }
  return labw;
}

__global__ __launch_bounds__(256) void kA(
    const float* __restrict__ emb, const int* __restrict__ inst,
    const float* __restrict__ kern, const float* __restrict__ mask,
    float* __restrict__ ws) {
  const int b = blockIdx.y;
  const int t = threadIdx.x;
  __shared__ float s_cnt[LBL];
  __shared__ float s_sum[4 * 33];
  __shared__ float s_cta[LBL];
  if (t < LBL) { s_cnt[t] = 0.f; s_cta[t] = 0.f; }
  if (t < 4 * 33) s_sum[t] = 0.f;
  __syncthreads();

  const long base = (long)b * NPIX;
  const float* ebase = emb + (long)b * 4 * NPIX;
  const int4* ip = (const int4*)(inst + base);
  const float4* kp = (const float4*)(kern + base);
  const float4* mp = (const float4*)(mask + base);
  const float4* p0 = (const float4*)(ebase);
  const float4* p1 = (const float4*)(ebase + NPIX);
  const float4* p2 = (const float4*)(ebase + 2 * NPIX);
  const float4* p3 = (const float4*)(ebase + 3 * NPIX);

  const int q0 = blockIdx.x * QPB + t;
  const int q1 = q0 + 256;
  const bool v1 = (q1 < NQ);

  const int4 iva = ip[q0];
  const float4 kva = kp[q0], mva = mp[q0];
  const float4 ea0 = p0[q0], ea1 = p1[q0], ea2 = p2[q0], ea3 = p3[q0];
  int4 ivb;
  float4 kvb, mvb, fb0, fb1, fb2, fb3;
  if (v1) {
    ivb = ip[q1]; kvb = kp[q1]; mvb = mp[q1];
    fb0 = p0[q1]; fb1 = p1[q1]; fb2 = p2[q1]; fb3 = p3[q1];
  }

  bool has0 = false;
  unsigned int* labp = (unsigned int*)(ws + LAB_BASE) + (size_t)b * NQ;
  labp[q0] = procQuad(iva, kva, mva, ea0, ea1, ea2, ea3, s_cnt, s_sum, s_cta, has0);
  if (v1)
    labp[q1] = procQuad(ivb, kvb, mvb, fb0, fb1, fb2, fb3, s_cnt, s_sum, s_cta, has0);

  if (has0) s_cnt[0] = 1.0f;
  __syncthreads();
  float* po = ws + PA_BASE + ((size_t)b * NBA + blockIdx.x) * 192;
  if (t < 192) {
    float v;
    if (t < 32) v = s_cnt[t];
    else if (t < 160) {
      const int e = t - 32;
      v = s_sum[(e & 3) * 33 + (e >> 2)];
    } else v = s_cta[t - 160];
    po[t] = v;
  }
}

__global__ __launch_bounds__(256) void kB(float* __restrict__ ws) {
  const int b = blockIdx.y;
  const int col = blockIdx.x * 4 + (threadIdx.x >> 6);
  const int lane = threadIdx.x & 63;
  const float* pa = ws + PA_BASE + (size_t)b * NBA * 192 + col;
  float s = 0.f;
  for (int g = lane; g < NBA; g += 64) s += pa[(size_t)g * 192];
#pragma unroll
  for (int o = 32; o > 0; o >>= 1) s += __shfl_down(s, o);
  if (lane == 0) ws[RED_BASE + b * 256 + col] = s;
}

__device__ __forceinline__ void aggQuadF(const unsigned int lw,
    const float4 e0, const float4 e1, const float4 e2, const float4 e3,
    const float* __restrict__ s_mean, float* __restrict__ s_val) {
  const float c0[4] = {e0.x, e0.y, e0.z, e0.w};
  const float c1[4] = {e1.x, e1.y, e1.z, e1.w};
  const float c2[4] = {e2.x, e2.y, e2.z, e2.w};
  const float c3[4] = {e3.x, e3.y, e3.z, e3.w};
#pragma unroll
  for (int j = 0; j < 4; j++) {
    const int li = (lw >> (8 * j)) & 0xFF;
    if (li > 0) {
      const float d0 = c0[j] - s_mean[li * 4 + 0];
      const float d1 = c1[j] - s_mean[li * 4 + 1];
      const float d2 = c2[j] - s_mean[li * 4 + 2];
      const float d3 = c3[j] - s_mean[li * 4 + 3];
      const float sq = d0 * d0 + d1 * d1 + d2 * d2 + d3 * d3;
      const float dist = (sq > 0.f) ? sqrtf(sq) : 0.f;
      const float tt = fmaxf(dist - DELTA_AGG, 0.f);
      atomicAdd(&s_val[li], logf(fmaf(tt, tt, 1.0f)));
    }
  }
}

__global__ __launch_bounds__(256) void kC(const float* __restrict__ emb,
                                          float* __restrict__ ws) {
  const int b = blockIdx.y;
  const int t = threadIdx.x;
  __shared__ float s_mean[LBL * 4];
  __shared__ float s_val[LBL];
  const float* rd = ws + RED_BASE + b * 256;
  if (t < LBL * 4) {
    const int l = t >> 2;
    s_mean[t] = (l == 0) ? 0.f : rd[32 + t] / fmaxf(rd[l], 1.0f);
  }
  if (t < LBL) s_val[t] = 0.f;
  __syncthreads();

  const unsigned int* labp = (const unsigned int*)(ws + LAB_BASE) + (size_t)b * NQ;
  const float* ebase = emb + (long)b * 4 * NPIX;
  const float4* p0 = (const float4*)(ebase);
  const float4* p1 = (const float4*)(ebase + NPIX);
  const float4* p2 = (const float4*)(ebase + 2 * NPIX);
  const float4* p3 = (const float4*)(ebase + 3 * NPIX);
  const int q0 = blockIdx.x * QPB + t;
  const int q1 = q0 + 256;
  const bool v1 = (q1 < NQ);

  const unsigned int lwa = labp[q0];
  const float4 ea0 = p0[q0], ea1 = p1[q0], ea2 = p2[q0], ea3 = p3[q0];
  unsigned int lwb = 0;
  float4 fb0, fb1, fb2, fb3;
  if (v1) {
    lwb = labp[q1];
    fb0 = p0[q1]; fb1 = p1[q1]; fb2 = p2[q1]; fb3 = p3[q1];
  }

  aggQuadF(lwa, ea0, ea1, ea2, ea3, s_mean, s_val);
  if (v1) aggQuadF(lwb, fb0, fb1, fb2, fb3, s_mean, s_val);

  __syncthreads();
  float* po = ws + PC_BASE + ((size_t)b * NBA + blockIdx.x) * 32;
  if (t < 32) po[t] = s_val[t];
}

__global__ __launch_bounds__(1024) void kD(const float* __restrict__ ws,
                                           float* __restrict__ out) {
  const int b = blockIdx.x;
  const int t = threadIdx.x;
  const int col = t >> 5, sub = t & 31;
  const float* pc = ws + PC_BASE + (size_t)b * NBA * 32 + col;
  float s = 0.f;
  for (int g = sub; g < NBA; g += 32) s += pc[(size_t)g * 32];
  __shared__ float red[LBL][33];
  red[col][sub] = s;

  const float* rd = ws + RED_BASE + b * 256;
  __shared__ float sm[LBL * 4];
  __shared__ float scc[LBL];
  __shared__ float sca[LBL];
  if (t >= 512 && t < 640) {
    const int e = t - 512, l = e >> 2;
    sm[e] = (l == 0) ? 0.f : rd[32 + e] / fmaxf(rd[l], 1.0f);
  } else if (t >= 640 && t < 672) {
    scc[t - 640] = rd[t - 640];
  } else if (t >= 672 && t < 704) {
    sca[t - 672] = rd[160 + (t - 672)];
  }
  __syncthreads();
  __shared__ float sv[LBL];
  if (t < 32) {
    float v = 0.f;
#pragma unroll
    for (int k = 0; k < 32; k++) v += red[t][k];
    sv[t] = v;
  }
  __syncthreads();

  if (t < 64) {
    const int lane = t;
    const bool pres = (lane < LBL) && (scc[lane & 31] > 0.f);
    const unsigned long long bal_p = __ballot(pres);
    const int num_instance = __popcll(bal_p);
    const bool nz = pres && (lane > 0);
    const unsigned long long bal_nz = __ballot(nz);

    float agg = 0.f;
    if (nz) agg = sv[lane] / fmaxf(sca[lane], 1.0f);

    float reg = 0.f;
    if (pres) {
      float sq = 0.f;
#pragma unroll
      for (int d = 0; d < 4; d++) sq += sm[lane * 4 + d] * sm[lane * 4 + d];
      const float nrm = (sq > 0.f) ? sqrtf(sq) : 0.f;
      reg = logf(nrm + 1.0f);
    }

    float dis = 0.f, npair = 0.f;
    for (int pi = lane; pi < LBL * LBL; pi += 64) {
      const int i = pi >> 5, j = pi & 31;
      if (i != j && ((bal_nz >> i) & 1ull) && ((bal_nz >> j) & 1ull)) {
        float sq = 0.f;
#pragma unroll
        for (int d = 0; d < 4; d++) {
          const float df = sm[i * 4 + d] - sm[j * 4 + d];
          sq += df * df;
        }
        const float pdist = (sq > 0.f) ? sqrtf(sq) : 0.f;
        const float tt = fmaxf(2.0f * DELTA_DIS - pdist, 0.f);
        dis += logf(fmaf(tt, tt, 1.0f));
        npair += 1.0f;
      }
    }

#pragma unroll
    for (int o = 32; o > 0; o >>= 1) {
      agg += __shfl_down(agg, o);
      reg += __shfl_down(reg, o);
      dis += __shfl_down(dis, o);
      npair += __shfl_down(npair, o);
    }

    if (lane == 0) {
      const float l_agg = agg / fmaxf((float)(num_instance - 1), 1.0f);
      const float l_dis = (num_instance > 2) ? dis / fmaxf(npair, 1.0f) : 0.f;
      const float l_reg = reg / fmaxf((float)num_instance, 1.0f) * REG_W;
      const float loss = l_agg + l_dis + l_reg;
      out[b] = (num_instance <= 1) ? 0.f : loss;
    }
  }
}

extern "C" void kernel_launch(void* const* d_in, const int* in_sizes, int n_in,
                              void* d_out, int out_size, void* d_ws,
                              size_t ws_size, hipStream_t stream) {
  const float* emb = (const float*)d_in[0];
  const int* instance = (const int*)d_in[1];
  const float* kern = (const float*)d_in[2];
  const float* mask = (const float*)d_in[3];
  float* out = (float*)d_out;
  float* ws = (float*)d_ws;

  dim3 gridA(NBA, BATCH);
  // --- ablation dispatches (write dummy ws regions only; decompose kA) ---
  kA_synld<<<gridA, 256, 0, stream>>>(ws);                       // atomics only
  kA_noat<<<gridA, 256, 0, stream>>>(emb, instance, kern, mask, ws);  // loads only
  // --- production chain (round-2 proven) ---
  kA<<<gridA, 256, 0, stream>>>(emb, instance, kern, mask, ws);
  dim3 gridB(48, BATCH);
  kB<<<gridB, 256, 0, stream>>>(ws);
  kC<<<gridA, 256, 0, stream>>>(emb, ws);
  kD<<<BATCH, 1024, 0, stream>>>(ws, out);
}